// Round 1
// baseline (44.216 us; speedup 1.0000x reference)
//
#include <hip/hip_runtime.h>
#include <hip/hip_bf16.h>

#define NCLS 64
#define NSUP 5
#define NQRY 15
#define DIM  4096
#define NQTOT (NCLS * NQRY)   // 960

typedef __attribute__((ext_vector_type(8))) short short8;
typedef __attribute__((ext_vector_type(4))) float f32x4;

__device__ __forceinline__ unsigned short f2bf(float f) {
    unsigned int u = __float_as_uint(f);
    u += 0x7FFFu + ((u >> 16) & 1u);   // RNE
    return (unsigned short)(u >> 16);
}
__device__ __forceinline__ float bf2f(unsigned short s) {
    return __uint_as_float(((unsigned int)s) << 16);
}

// Kernel 1: blocks [0,64): prototype = mean of 5 support rows -> bf16 P, fp32 ||p||^2
//           blocks [64,1024): convert one query row fp32 -> bf16 Q
__global__ __launch_bounds__(256) void proto_prep_kernel(
    const float* __restrict__ in, unsigned short* __restrict__ P,
    unsigned short* __restrict__ Q, float* __restrict__ pnorm,
    float* __restrict__ out)
{
    const int b = blockIdx.x, t = threadIdx.x;
    if (b < NCLS) {
        const float* base = in + (size_t)b * (NSUP + NQRY) * DIM;
        float pn = 0.f;
        #pragma unroll
        for (int j = 0; j < 4; ++j) {
            const int d = (t + 256 * j) * 4;
            float4 s0 = *(const float4*)(base + 0 * DIM + d);
            float4 s1 = *(const float4*)(base + 1 * DIM + d);
            float4 s2 = *(const float4*)(base + 2 * DIM + d);
            float4 s3 = *(const float4*)(base + 3 * DIM + d);
            float4 s4 = *(const float4*)(base + 4 * DIM + d);
            float ax = 0.2f * (s0.x + s1.x + s2.x + s3.x + s4.x);
            float ay = 0.2f * (s0.y + s1.y + s2.y + s3.y + s4.y);
            float az = 0.2f * (s0.z + s1.z + s2.z + s3.z + s4.z);
            float aw = 0.2f * (s0.w + s1.w + s2.w + s3.w + s4.w);
            ushort4 o;
            o.x = f2bf(ax); o.y = f2bf(ay); o.z = f2bf(az); o.w = f2bf(aw);
            *(ushort4*)(P + (size_t)b * DIM + d) = o;
            // ||p||^2 from the ROUNDED values (consistent with the 2*q.p term)
            float rx = bf2f(o.x), ry = bf2f(o.y), rz = bf2f(o.z), rw = bf2f(o.w);
            pn += rx * rx + ry * ry + rz * rz + rw * rw;
        }
        // block reduce pn (256 threads = 4 waves)
        #pragma unroll
        for (int m = 32; m > 0; m >>= 1) pn += __shfl_xor(pn, m);
        __shared__ float red[4];
        if ((t & 63) == 0) red[t >> 6] = pn;
        __syncthreads();
        if (t == 0) {
            pnorm[b] = red[0] + red[1] + red[2] + red[3];
            if (b == 0) { out[0] = 0.f; out[1] = 0.f; }
        }
    } else {
        const int qi = b - NCLS;
        const int row = (qi / NQRY) * (NSUP + NQRY) + NSUP + (qi % NQRY);
        const float* src = in + (size_t)row * DIM;
        unsigned short* dst = Q + (size_t)qi * DIM;
        #pragma unroll
        for (int j = 0; j < 4; ++j) {
            const int d = (t + 256 * j) * 4;
            float4 v = *(const float4*)(src + d);
            ushort4 o;
            o.x = f2bf(v.x); o.y = f2bf(v.y); o.z = f2bf(v.z); o.w = f2bf(v.w);
            *(ushort4*)(dst + d) = o;
        }
    }
}

// Kernel 2: 60 blocks x 256 threads (4 waves). Block = 16 queries, wave w = classes [16w,16w+16).
// s[q,c] = 2*q.p - ||p||^2 via mfma_f32_16x16x32_bf16, then fused row log_softmax/argmax.
__global__ __launch_bounds__(256) void proto_gemm_kernel(
    const unsigned short* __restrict__ Q, const unsigned short* __restrict__ P,
    const float* __restrict__ pnorm, float* __restrict__ out)
{
    __shared__ float s_lds[16][64];
    __shared__ float red_l[16], red_a[16];

    const int t = threadIdx.x;
    const int w = t >> 6, lane = t & 63;
    const int m = lane & 15;      // A row (query) / B col (class) / C col (class)
    const int g = lane >> 4;      // k-group
    const int qbase = blockIdx.x * 16;
    const int cbase = w * 16;

    const short8* ap = (const short8*)(Q + (size_t)(qbase + m) * DIM + g * 8);
    const short8* bp = (const short8*)(P + (size_t)(cbase + m) * DIM + g * 8);

    f32x4 acc = {0.f, 0.f, 0.f, 0.f};
    #pragma unroll 8
    for (int kk = 0; kk < DIM / 32; ++kk) {   // 128 K-steps, 32 shorts = 4 short8 stride
        short8 a = ap[kk * 4];
        short8 bb = bp[kk * 4];
        acc = __builtin_amdgcn_mfma_f32_16x16x32_bf16(a, bb, acc, 0, 0, 0);
    }

    const float pn = pnorm[cbase + m];        // C col = lane&15
    #pragma unroll
    for (int j = 0; j < 4; ++j) {
        const int row = g * 4 + j;            // C row = (lane>>4)*4 + j
        s_lds[row][cbase + m] = 2.f * acc[j] - pn;
    }
    __syncthreads();

    // softmax: 16 threads per row; thread t -> row r = t>>4, owns classes idx+16*i
    const int r = t >> 4, idx = t & 15;
    float v[4];
    #pragma unroll
    for (int i = 0; i < 4; ++i) v[i] = s_lds[r][idx + 16 * i];

    float mx = v[0]; int am = idx;
    #pragma unroll
    for (int i = 1; i < 4; ++i)
        if (v[i] > mx) { mx = v[i]; am = idx + 16 * i; }
    #pragma unroll
    for (int msk = 1; msk < 16; msk <<= 1) {
        float vo = __shfl_xor(mx, msk);
        int   ao = __shfl_xor(am, msk);
        if (vo > mx || (vo == mx && ao < am)) { mx = vo; am = ao; }
    }
    float se = 0.f;
    #pragma unroll
    for (int i = 0; i < 4; ++i) se += __expf(v[i] - mx);
    #pragma unroll
    for (int msk = 1; msk < 16; msk <<= 1) se += __shfl_xor(se, msk);
    const float lse = mx + __logf(se);

    const int qi = qbase + r;
    const int cc = qi / NQRY;                 // correct class for this query
    if (idx == 0) {
        red_l[r] = s_lds[r][cc] - lse;        // log p at correct class
        red_a[r] = (am == cc) ? 1.f : 0.f;
    }
    __syncthreads();
    if (t == 0) {
        float sl = 0.f, sa = 0.f;
        #pragma unroll
        for (int i = 0; i < 16; ++i) { sl += red_l[i]; sa += red_a[i]; }
        atomicAdd(out + 0, sl * (-1.f / (float)NQTOT));
        atomicAdd(out + 1, sa * (1.f / (float)NQTOT));
    }
}

extern "C" void kernel_launch(void* const* d_in, const int* in_sizes, int n_in,
                              void* d_out, int out_size, void* d_ws, size_t ws_size,
                              hipStream_t stream) {
    const float* in = (const float*)d_in[0];
    float* out = (float*)d_out;
    char* ws = (char*)d_ws;

    unsigned short* P = (unsigned short*)ws;                      // 64*4096*2   = 524288 B
    unsigned short* Q = (unsigned short*)(ws + 524288);           // 960*4096*2  = 7864320 B
    float* pnorm = (float*)(ws + 524288 + 7864320);               // 256 B

    hipLaunchKernelGGL(proto_prep_kernel, dim3(NCLS + NQTOT), dim3(256), 0, stream,
                       in, P, Q, pnorm, out);
    hipLaunchKernelGGL(proto_gemm_kernel, dim3(NQTOT / 16), dim3(256), 0, stream,
                       Q, P, pnorm, out);
}

// Round 2
// 34.687 us; speedup vs baseline: 1.2747x; 1.2747x over previous
//
#include <hip/hip_runtime.h>
#include <hip/hip_bf16.h>

#define NCLS 64
#define NSUP 5
#define NQRY 15
#define DIM  4096
#define NQTOT (NCLS * NQRY)   // 960

typedef __attribute__((ext_vector_type(8))) short short8;
typedef __attribute__((ext_vector_type(4))) float f32x4;

__device__ __forceinline__ unsigned short f2bf(float f) {
    unsigned int u = __float_as_uint(f);
    u += 0x7FFFu + ((u >> 16) & 1u);   // RNE
    return (unsigned short)(u >> 16);
}
__device__ __forceinline__ float bf2f(unsigned short s) {
    return __uint_as_float(((unsigned int)s) << 16);
}

// K1: prototypes only. 256 blocks: class c = b>>2, d-chunk dc = b&3 (1024 dims).
// Writes bf16 P[c][D] and partial ||p||^2 -> pnp[c*4+dc]. Also zeroes out[0..1].
__global__ __launch_bounds__(256) void proto_prep(
    const float* __restrict__ in, unsigned short* __restrict__ P,
    float* __restrict__ pnp, float* __restrict__ out)
{
    const int b = blockIdx.x, t = threadIdx.x;
    const int c = b >> 2, dc = b & 3;
    const int d = dc * 1024 + t * 4;
    const float* base = in + (size_t)c * (NSUP + NQRY) * DIM + d;

    float4 s0 = *(const float4*)(base + 0 * DIM);
    float4 s1 = *(const float4*)(base + 1 * DIM);
    float4 s2 = *(const float4*)(base + 2 * DIM);
    float4 s3 = *(const float4*)(base + 3 * DIM);
    float4 s4 = *(const float4*)(base + 4 * DIM);
    float ax = 0.2f * (s0.x + s1.x + s2.x + s3.x + s4.x);
    float ay = 0.2f * (s0.y + s1.y + s2.y + s3.y + s4.y);
    float az = 0.2f * (s0.z + s1.z + s2.z + s3.z + s4.z);
    float aw = 0.2f * (s0.w + s1.w + s2.w + s3.w + s4.w);
    ushort4 o;
    o.x = f2bf(ax); o.y = f2bf(ay); o.z = f2bf(az); o.w = f2bf(aw);
    *(ushort4*)(P + (size_t)c * DIM + d) = o;

    // ||p||^2 from the ROUNDED values (consistent with the 2*q.p MFMA term)
    float rx = bf2f(o.x), ry = bf2f(o.y), rz = bf2f(o.z), rw = bf2f(o.w);
    float pn = rx * rx + ry * ry + rz * rz + rw * rw;

    #pragma unroll
    for (int m = 32; m > 0; m >>= 1) pn += __shfl_xor(pn, m);
    __shared__ float red[4];
    if ((t & 63) == 0) red[t >> 6] = pn;
    __syncthreads();
    if (t == 0) {
        pnp[c * 4 + dc] = red[0] + red[1] + red[2] + red[3];
        if (b == 0) { out[0] = 0.f; out[1] = 0.f; }
    }
}

// K2: 60 blocks x 1024 threads (16 waves). Block = 16 queries x 64 classes.
// Wave w owns K-chunk [w*256, w*256+256) and ALL four 16-class tiles
// (4 independent MFMA chains, length 8). A (queries) converted fp32->bf16
// on the fly via v_perm truncation-pack. Partials reduced via LDS, then
// fused per-row (per-wave) log_softmax + argmax + loss/acc accumulation.
__global__ __launch_bounds__(1024) void proto_main(
    const float* __restrict__ in, const unsigned short* __restrict__ P,
    const float* __restrict__ pnp, float* __restrict__ out)
{
    __shared__ float part[16 * 16 * 64];   // [kc][row][col], 64 KB
    __shared__ float red_l[16], red_a[16];

    const int tid = threadIdx.x;
    const int w = tid >> 6, lane = tid & 63;
    const int m = lane & 15;       // A row (query) / B col (class)
    const int g = lane >> 4;       // k-group within MFMA step
    const int qbase = blockIdx.x * 16;

    // A: query row qbase+m, fp32 from the original input
    const int qi0 = qbase + m;
    const int rowA = (qi0 / NQRY) * (NSUP + NQRY) + NSUP + (qi0 % NQRY);
    const float* ap = in + (size_t)rowA * DIM + w * 256 + g * 8;
    const unsigned short* bp = P + (size_t)m * DIM + w * 256 + g * 8;

    f32x4 acc[4];
    #pragma unroll
    for (int i = 0; i < 4; ++i) acc[i] = (f32x4){0.f, 0.f, 0.f, 0.f};

    #pragma unroll
    for (int s = 0; s < 8; ++s) {
        const int ko = s * 32;
        float4 a0 = *(const float4*)(ap + ko);
        float4 a1 = *(const float4*)(ap + ko + 4);
        // truncation-pack two fp32 -> packed bf16x2 (1 v_perm each)
        unsigned p0 = __builtin_amdgcn_perm(__float_as_uint(a0.y), __float_as_uint(a0.x), 0x07060302u);
        unsigned p1 = __builtin_amdgcn_perm(__float_as_uint(a0.w), __float_as_uint(a0.z), 0x07060302u);
        unsigned p2 = __builtin_amdgcn_perm(__float_as_uint(a1.y), __float_as_uint(a1.x), 0x07060302u);
        unsigned p3 = __builtin_amdgcn_perm(__float_as_uint(a1.w), __float_as_uint(a1.z), 0x07060302u);
        union { unsigned u[4]; short8 v; } au;
        au.u[0] = p0; au.u[1] = p1; au.u[2] = p2; au.u[3] = p3;
        short8 af = au.v;

        short8 b0 = *(const short8*)(bp + ko);
        short8 b1 = *(const short8*)(bp + ko + 16 * DIM);
        short8 b2 = *(const short8*)(bp + ko + 32 * DIM);
        short8 b3 = *(const short8*)(bp + ko + 48 * DIM);
        acc[0] = __builtin_amdgcn_mfma_f32_16x16x32_bf16(af, b0, acc[0], 0, 0, 0);
        acc[1] = __builtin_amdgcn_mfma_f32_16x16x32_bf16(af, b1, acc[1], 0, 0, 0);
        acc[2] = __builtin_amdgcn_mfma_f32_16x16x32_bf16(af, b2, acc[2], 0, 0, 0);
        acc[3] = __builtin_amdgcn_mfma_f32_16x16x32_bf16(af, b3, acc[3], 0, 0, 0);
    }

    // partial store: C layout col=lane&15, row=(lane>>4)*4+j  [m89]
    #pragma unroll
    for (int cg = 0; cg < 4; ++cg) {
        #pragma unroll
        for (int j = 0; j < 4; ++j) {
            part[(w * 16 + g * 4 + j) * 64 + cg * 16 + m] = acc[cg][j];
        }
    }
    __syncthreads();

    // reduce over 16 K-chunks + fused softmax. wave = row, lane = class col.
    const int row = tid >> 6, col = tid & 63;
    float v = 0.f;
    #pragma unroll
    for (int kc = 0; kc < 16; ++kc) v += part[(kc * 16 + row) * 64 + col];
    float4 pp = *(const float4*)(pnp + col * 4);
    v = 2.f * v - (pp.x + pp.y + pp.z + pp.w);

    float mx = v; int am = col;
    #pragma unroll
    for (int msk = 1; msk < 64; msk <<= 1) {
        float vo = __shfl_xor(mx, msk);
        int   ao = __shfl_xor(am, msk);
        if (vo > mx || (vo == mx && ao < am)) { mx = vo; am = ao; }
    }
    float se = __expf(v - mx);
    #pragma unroll
    for (int msk = 1; msk < 64; msk <<= 1) se += __shfl_xor(se, msk);
    const float lse = mx + __logf(se);

    const int cc = (qbase + row) / NQRY;   // correct class (uniform per wave)
    const float vc = __shfl(v, cc);
    if (col == 0) {
        red_l[row] = vc - lse;
        red_a[row] = (am == cc) ? 1.f : 0.f;
    }
    __syncthreads();
    if (tid == 0) {
        float sl = 0.f, sa = 0.f;
        #pragma unroll
        for (int i = 0; i < 16; ++i) { sl += red_l[i]; sa += red_a[i]; }
        atomicAdd(out + 0, sl * (-1.f / (float)NQTOT));
        atomicAdd(out + 1, sa * (1.f / (float)NQTOT));
    }
}

extern "C" void kernel_launch(void* const* d_in, const int* in_sizes, int n_in,
                              void* d_out, int out_size, void* d_ws, size_t ws_size,
                              hipStream_t stream) {
    const float* in = (const float*)d_in[0];
    float* out = (float*)d_out;
    char* ws = (char*)d_ws;

    unsigned short* P = (unsigned short*)ws;               // 64*4096*2 = 524288 B
    float* pnp = (float*)(ws + 524288);                    // 64*4*4    = 1024 B

    hipLaunchKernelGGL(proto_prep, dim3(256), dim3(256), 0, stream, in, P, pnp, out);
    hipLaunchKernelGGL(proto_main, dim3(NQTOT / 16), dim3(1024), 0, stream, in, P, pnp, out);
}